// Round 9
// baseline (294.715 us; speedup 1.0000x reference)
//
#include <hip/hip_runtime.h>
#include <hip/hip_bf16.h>

// Attention fwd with materialized p_attn.
// B=16, S=2048, D=64, f32 in/out. d_out = [out (B,S,D) | p_attn (B,S,S)] f32.
#define BN 16
#define SN 2048
#define DN 64
#define QB 16

// K1 (attn_pass1): 4 waves/block, 512 keys per wave
#define KSEG1 512
#define NC1 16

// fallback (R6 structure): 8 waves, 256 keys per wave
#define NWAVE 8
#define KSEG 256
#define SROW 2056

#define SC_L2E 0.18033688011112042f   // 0.125 * log2(e)
#define BI_L2E 11.541560327111707f    // 8 * log2(e): p~ = exp(s - 8)

typedef __attribute__((ext_vector_type(8))) short bf16x8;
typedef __attribute__((ext_vector_type(4))) short bf16x4;
typedef __attribute__((ext_vector_type(4))) float f32x4;
typedef __attribute__((ext_vector_type(4))) int   i32x4;
typedef __attribute__((ext_vector_type(2))) unsigned u32x2;
typedef __attribute__((ext_vector_type(4))) unsigned u32x4;

static __device__ __forceinline__ short f2bf(float f) {
    __hip_bfloat16 h = __float2bfloat16(f);
    union { __hip_bfloat16 h; short s; } u; u.h = h;
    return u.s;
}
static __device__ __forceinline__ float bf2f(short s) {
    union { unsigned u; float f; } v; v.u = ((unsigned)(unsigned short)s) << 16;
    return v.f;
}
static __device__ __forceinline__ float uf(unsigned u) {
    union { unsigned u; float f; } v; v.u = u;
    return v.f;
}
static __device__ __forceinline__ unsigned pk2(float lo, float hi) {
    return ((unsigned)(unsigned short)f2bf(lo)) |
           (((unsigned)(unsigned short)f2bf(hi)) << 16);
}
static __device__ __forceinline__ float fast_exp2(float x) {
#if __has_builtin(__builtin_amdgcn_exp2f)
    return __builtin_amdgcn_exp2f(x);
#else
    return exp2f(x);
#endif
}

// ---- prep: K->bf16 [B][S][D]; V->bf16 transposed [B][D][S]; mask->f32 bias ----
__global__ __launch_bounds__(256)
void prep_kv(const float* __restrict__ K, const float* __restrict__ V,
             const int* __restrict__ M,
             short* __restrict__ Kp, short* __restrict__ Vt, float* __restrict__ Mf)
{
    __shared__ short vt[64][68];
    const int b  = blockIdx.x >> 5;
    const int s0 = (blockIdx.x & 31) << 6;
    const int tid = threadIdx.x;
    const int sr = tid >> 4;
    const int dc = (tid & 15) << 2;
    const float* Kb = K + ((size_t)b * SN + s0) * DN;
    const float* Vb = V + ((size_t)b * SN + s0) * DN;
    short* Kpb = Kp + ((size_t)b * SN + s0) * DN;
    #pragma unroll
    for (int i = 0; i < 4; ++i) {
        const int s = sr + i * 16;
        f32x4 kv = *(const f32x4*)(Kb + (size_t)s * DN + dc);
        f32x4 vv = *(const f32x4*)(Vb + (size_t)s * DN + dc);
        bf16x4 k4, v4;
        #pragma unroll
        for (int j = 0; j < 4; ++j) { k4[j] = f2bf(kv[j]); v4[j] = f2bf(vv[j]); }
        *(bf16x4*)(Kpb + (size_t)s * DN + dc) = k4;
        *(bf16x4*)&vt[s][dc] = v4;
    }
    if (tid < 64) {
        const int m = M[(size_t)b * SN + s0 + tid];
        Mf[(size_t)b * SN + s0 + tid] = m ? -BI_L2E : -1e9f;
    }
    __syncthreads();
    const int d  = tid >> 2;
    const int sg = (tid & 3) << 4;
    short* dst = Vt + ((size_t)b * DN + d) * SN + s0 + sg;
    bf16x8 w0, w1;
    #pragma unroll
    for (int j = 0; j < 8; ++j) { w0[j] = vt[sg + j][d]; w1[j] = vt[sg + 8 + j][d]; }
    *(bf16x8*)dst = w0;
    *(bf16x8*)(dst + 8) = w1;
}

// ---- K1: single pass. QK^T -> exp -> {NT-store p~ bf16 to ws, in-place PV}.
// No LDS / no barriers in the main loop; p~ store does NOT wait on the row sum.
// Writes Lf = 1/l per row for K2, and the normalized O output.
__global__ __launch_bounds__(256, 6)
void attn_pass1(const float* __restrict__ Q, const short* __restrict__ Kp,
                const short* __restrict__ Vt, const float* __restrict__ Mf,
                short* __restrict__ Pt, float* __restrict__ Lf,
                float* __restrict__ out)
{
    __shared__ float obuf[4 * QB * DN];   // 16 KB
    __shared__ float lred[4 * QB];
    __shared__ float lfin[QB];

    const int tid = threadIdx.x;
    const int wv = tid >> 6, ln = tid & 63;
    const int lq = ln & 15, lg = ln >> 4;

    // XCD-bijective swizzle (2048 blocks / 8 XCDs): 2 batches per XCD.
    const int lb = ((blockIdx.x & 7) << 8) | (blockIdx.x >> 3);
    const int bb = lb >> 7;
    const int q0 = (lb & 127) << 4;

    const float* Qb = Q + ((size_t)bb * SN + q0) * DN;
    const short* Kpb = Kp + (size_t)bb * SN * DN;
    const short* Vtb = Vt + (size_t)bb * DN * SN;
    const float* Fb = Mf + (size_t)bb * SN;
    float* out_o = out + ((size_t)bb * SN + q0) * DN;

    // Q fragment (B-operand of swapped QK^T): Q[col=lq][d=8*lg+j]
    bf16x8 qf0, qf1;
    {
        const float* src = Qb + lq * DN + lg * 8;
        f32x4 a = *(const f32x4*)src;
        f32x4 b = *(const f32x4*)(src + 4);
        f32x4 c = *(const f32x4*)(src + 32);
        f32x4 d = *(const f32x4*)(src + 36);
        #pragma unroll
        for (int j = 0; j < 4; ++j) {
            qf0[j] = f2bf(a[j]); qf0[4 + j] = f2bf(b[j]);
            qf1[j] = f2bf(c[j]); qf1[4 + j] = f2bf(d[j]);
        }
    }

    const int k0 = wv * KSEG1;
    const short* kptr = Kpb + (size_t)(k0 + lq) * DN + lg * 8;   // +c*2048/chunk
    const float* fptr = Fb + k0 + 4 * lg;                        // +c*32 (+16)
    const short* vp0 = Vtb + (size_t)(0 * 16 + lq) * SN + k0 + 4 * lg;
    const short* vp1 = Vtb + (size_t)(1 * 16 + lq) * SN + k0 + 4 * lg;
    const short* vp2 = Vtb + (size_t)(2 * 16 + lq) * SN + k0 + 4 * lg;
    const short* vp3 = Vtb + (size_t)(3 * 16 + lq) * SN + k0 + 4 * lg;
    short* ptp = Pt + (size_t)(bb * SN + q0 + lq) * SN + k0 + 4 * lg;

    f32x4 oacc[4];
    #pragma unroll
    for (int nt = 0; nt < 4; ++nt) oacc[nt] = (f32x4){0.f, 0.f, 0.f, 0.f};
    float lsum = 0.f;

    #pragma unroll 2
    for (int c = 0; c < NC1; ++c) {
        const bf16x8 kf0 = *(const bf16x8*)(kptr + c * 2048);
        const bf16x8 kf1 = *(const bf16x8*)(kptr + c * 2048 + 32);
        const bf16x8 kf2 = *(const bf16x8*)(kptr + c * 2048 + 1024);
        const bf16x8 kf3 = *(const bf16x8*)(kptr + c * 2048 + 1056);
        const f32x4 b0 = *(const f32x4*)(fptr + c * 32);
        const f32x4 b1 = *(const f32x4*)(fptr + c * 32 + 16);

        f32x4 a0 = {0.f, 0.f, 0.f, 0.f}, a1 = {0.f, 0.f, 0.f, 0.f};
        a0 = __builtin_amdgcn_mfma_f32_16x16x32_bf16(kf0, qf0, a0, 0, 0, 0);
        a0 = __builtin_amdgcn_mfma_f32_16x16x32_bf16(kf1, qf1, a0, 0, 0, 0);
        a1 = __builtin_amdgcn_mfma_f32_16x16x32_bf16(kf2, qf0, a1, 0, 0, 0);
        a1 = __builtin_amdgcn_mfma_f32_16x16x32_bf16(kf3, qf1, a1, 0, 0, 0);

        float p0[4], p1[4];
        #pragma unroll
        for (int r = 0; r < 4; ++r) {
            p0[r] = fast_exp2(fmaf(a0[r], SC_L2E, b0[r]));
            p1[r] = fast_exp2(fmaf(a1[r], SC_L2E, b1[r]));
            lsum += p0[r] + p1[r];
        }
        // pack p~ -> bf16 pairs; store unnormalized to ws (no dependence on l)
        union { unsigned u[4]; bf16x8 v; } pa;
        pa.u[0] = pk2(p0[0], p0[1]); pa.u[1] = pk2(p0[2], p0[3]);
        pa.u[2] = pk2(p1[0], p1[1]); pa.u[3] = pk2(p1[2], p1[3]);
        __builtin_nontemporal_store((u32x2){pa.u[0], pa.u[1]}, (u32x2*)(ptp + c * 32));
        __builtin_nontemporal_store((u32x2){pa.u[2], pa.u[3]}, (u32x2*)(ptp + c * 32 + 16));

        // in-place PV: A = packed quads (slot-permuted), B = V^T quads at same perm
        union { bf16x4 q[2]; bf16x8 v; } vf0, vf1, vf2, vf3;
        vf0.q[0] = *(const bf16x4*)(vp0 + c * 32); vf0.q[1] = *(const bf16x4*)(vp0 + c * 32 + 16);
        vf1.q[0] = *(const bf16x4*)(vp1 + c * 32); vf1.q[1] = *(const bf16x4*)(vp1 + c * 32 + 16);
        vf2.q[0] = *(const bf16x4*)(vp2 + c * 32); vf2.q[1] = *(const bf16x4*)(vp2 + c * 32 + 16);
        vf3.q[0] = *(const bf16x4*)(vp3 + c * 32); vf3.q[1] = *(const bf16x4*)(vp3 + c * 32 + 16);
        oacc[0] = __builtin_amdgcn_mfma_f32_16x16x32_bf16(pa.v, vf0.v, oacc[0], 0, 0, 0);
        oacc[1] = __builtin_amdgcn_mfma_f32_16x16x32_bf16(pa.v, vf1.v, oacc[1], 0, 0, 0);
        oacc[2] = __builtin_amdgcn_mfma_f32_16x16x32_bf16(pa.v, vf2.v, oacc[2], 0, 0, 0);
        oacc[3] = __builtin_amdgcn_mfma_f32_16x16x32_bf16(pa.v, vf3.v, oacc[3], 0, 0, 0);
    }

    // row sums (row = lq): reduce over lg groups, then waves via LDS
    lsum += __shfl_xor(lsum, 16);
    lsum += __shfl_xor(lsum, 32);
    if (lg == 0) lred[wv * QB + lq] = lsum;
    __syncthreads();
    if (tid < QB) {
        const float l = lred[tid] + lred[QB + tid] + lred[2 * QB + tid] + lred[3 * QB + tid];
        const float r = 1.f / l;
        lfin[tid] = r;
        Lf[(size_t)bb * SN + q0 + tid] = r;
    }

    // O epilogue: oacc[nt][r] = O[q=4lg+r][d=nt*16+lq]; cross-wave reduce in LDS
    #pragma unroll
    for (int nt = 0; nt < 4; ++nt) {
        #pragma unroll
        for (int r = 0; r < 4; ++r)
            obuf[(wv * QB + 4 * lg + r) * DN + nt * 16 + lq] = oacc[nt][r];
    }
    __syncthreads();
    #pragma unroll
    for (int i = 0; i < 4; ++i) {
        const int idx = tid + i * 256;
        const int q = idx >> 6, d = idx & 63;
        const float v = obuf[q * DN + d] + obuf[(QB + q) * DN + d] +
                        obuf[(2 * QB + q) * DN + d] + obuf[(3 * QB + q) * DN + d];
        out_o[(size_t)q * DN + d] = v * lfin[q];
    }
}

// ---- K2: pure streaming normalize. p = bf2f(p~) * (1/l). ----
__global__ __launch_bounds__(256)
void scale_p(const short* __restrict__ Pt, const float* __restrict__ Lf,
             float* __restrict__ out_p)
{
    const size_t NV = (size_t)BN * SN * SN / 8;   // vec8 tasks
    const size_t stride = (size_t)gridDim.x * blockDim.x;
    for (size_t i = (size_t)blockIdx.x * blockDim.x + threadIdx.x; i < NV; i += stride) {
        const size_t row = i >> 8;                // 256 vec8 per row
        const float rl = Lf[row];
        const u32x4 w = *(const u32x4*)(Pt + i * 8);
        f32x4 o0, o1;
        o0[0] = uf(w[0] << 16) * rl;  o0[1] = uf(w[0] & 0xffff0000u) * rl;
        o0[2] = uf(w[1] << 16) * rl;  o0[3] = uf(w[1] & 0xffff0000u) * rl;
        o1[0] = uf(w[2] << 16) * rl;  o1[1] = uf(w[2] & 0xffff0000u) * rl;
        o1[2] = uf(w[3] << 16) * rl;  o1[3] = uf(w[3] & 0xffff0000u) * rl;
        float* dst = out_p + i * 8;
        __builtin_nontemporal_store(o0, (f32x4*)dst);
        __builtin_nontemporal_store(o1, (f32x4*)(dst + 4));
    }
}

// ---- fallback: proven R6 single kernel (used when ws can't hold Pt) ----
template <int PRE>
__global__ __launch_bounds__(512, 2)
void attn_fallback(const float* __restrict__ Q, const float* __restrict__ K,
                   const float* __restrict__ V, const int* __restrict__ M,
                   const short* __restrict__ Kp, const short* __restrict__ Vt,
                   float* __restrict__ out)
{
    __shared__ short sbuf[QB * SROW];
    __shared__ float lred[NWAVE * QB];
    __shared__ float lfin[QB];

    const int tid = threadIdx.x;
    const int wv = tid >> 6, ln = tid & 63;
    const int lq = ln & 15, lg = ln >> 4;

    const int lb = ((blockIdx.x & 7) << 8) | (blockIdx.x >> 3);
    const int bb = lb >> 7;
    const int q0 = (lb & 127) << 4;

    const float* Qb = Q + ((size_t)bb * SN + q0) * DN;
    const float* Kb = K + (size_t)bb * SN * DN;
    const float* Vb = V + (size_t)bb * SN * DN;
    const short* Kpb = Kp + (size_t)bb * SN * DN;
    const short* Vtb = Vt + (size_t)bb * DN * SN;
    const int*   Mb = M + (size_t)bb * SN;
    float* out_o = out + ((size_t)bb * SN + q0) * DN;
    float* out_p = out + (size_t)BN * SN * DN + ((size_t)bb * SN + q0) * SN;

    bf16x8 qf[2];
    #pragma unroll
    for (int s = 0; s < 2; ++s) {
        const float* src = Qb + lq * DN + s * 32 + lg * 8;
        f32x4 a = *(const f32x4*)src;
        f32x4 b = *(const f32x4*)(src + 4);
        #pragma unroll
        for (int j = 0; j < 4; ++j) { qf[s][j] = f2bf(a[j]); qf[s][4 + j] = f2bf(b[j]); }
    }

    const int k0 = wv * KSEG;
    float lsum = 0.f;

    #pragma unroll 2
    for (int kb = k0; kb < k0 + KSEG; kb += 32) {
        bf16x8 kf0, kf1, kf2, kf3;
        if constexpr (PRE) {
            const short* kr = Kpb + (size_t)(kb + lq) * DN + lg * 8;
            kf0 = *(const bf16x8*)kr;
            kf1 = *(const bf16x8*)(kr + 32);
            kf2 = *(const bf16x8*)(kr + 16 * DN);
            kf3 = *(const bf16x8*)(kr + 16 * DN + 32);
        } else {
            const float* ks = Kb + (size_t)(kb + lq) * DN + lg * 8;
            #pragma unroll
            for (int j = 0; j < 8; ++j) {
                kf0[j] = f2bf(ks[j]);            kf1[j] = f2bf(ks[32 + j]);
                kf2[j] = f2bf(ks[16 * DN + j]);  kf3[j] = f2bf(ks[16 * DN + 32 + j]);
            }
        }
        const i32x4 mv0 = *(const i32x4*)&Mb[kb + 4 * lg];
        const i32x4 mv1 = *(const i32x4*)&Mb[kb + 16 + 4 * lg];

        f32x4 a0 = {0.f, 0.f, 0.f, 0.f}, a1 = {0.f, 0.f, 0.f, 0.f};
        a0 = __builtin_amdgcn_mfma_f32_16x16x32_bf16(kf0, qf[0], a0, 0, 0, 0);
        a0 = __builtin_amdgcn_mfma_f32_16x16x32_bf16(kf1, qf[1], a0, 0, 0, 0);
        a1 = __builtin_amdgcn_mfma_f32_16x16x32_bf16(kf2, qf[0], a1, 0, 0, 0);
        a1 = __builtin_amdgcn_mfma_f32_16x16x32_bf16(kf3, qf[1], a1, 0, 0, 0);

        float p0[4], p1[4];
        #pragma unroll
        for (int r = 0; r < 4; ++r) {
            p0[r] = mv0[r] ? fast_exp2(fmaf(a0[r], SC_L2E, -BI_L2E)) : 0.f;
            p1[r] = mv1[r] ? fast_exp2(fmaf(a1[r], SC_L2E, -BI_L2E)) : 0.f;
            lsum += p0[r] + p1[r];
        }
        u32x2 wa = {pk2(p0[0], p0[1]), pk2(p0[2], p0[3])};
        u32x2 wb = {pk2(p1[0], p1[1]), pk2(p1[2], p1[3])};
        *(u32x2*)&sbuf[lq * SROW + kb + 4 * lg] = wa;
        *(u32x2*)&sbuf[lq * SROW + kb + 16 + 4 * lg] = wb;
    }

    lsum += __shfl_xor(lsum, 16);
    lsum += __shfl_xor(lsum, 32);
    if (lg == 0) lred[wv * QB + lq] = lsum;
    __syncthreads();
    if (tid < QB) {
        float l = 0.f;
        #pragma unroll
        for (int w = 0; w < NWAVE; ++w) l += lred[w * QB + tid];
        lfin[tid] = 1.f / l;
    }
    __syncthreads();

    f32x4 oacc[4];
    #pragma unroll
    for (int nt = 0; nt < 4; ++nt) oacc[nt] = (f32x4){0.f, 0.f, 0.f, 0.f};

    #pragma unroll 2
    for (int c = 0; c < KSEG / 32; ++c) {
        const int kb = k0 + c * 32;
        bf16x8 pa = *(const bf16x8*)&sbuf[lq * SROW + kb + 8 * lg];
        #pragma unroll
        for (int nt = 0; nt < 4; ++nt) {
            bf16x8 vf;
            if constexpr (PRE) {
                vf = *(const bf16x8*)(Vtb + (size_t)(nt * 16 + lq) * SN + kb + 8 * lg);
            } else {
                const float* vsrc = Vb + (size_t)(kb + 8 * lg) * DN + nt * 16 + lq;
                #pragma unroll
                for (int j = 0; j < 8; ++j) vf[j] = f2bf(vsrc[(size_t)j * DN]);
            }
            oacc[nt] = __builtin_amdgcn_mfma_f32_16x16x32_bf16(pa, vf, oacc[nt], 0, 0, 0);
        }
        #pragma unroll
        for (int j = 0; j < 2; ++j) {
            const int q = 2 * c + j;
            const float rl = lfin[q];
            bf16x4 s4 = *(const bf16x4*)&sbuf[q * SROW + k0 + ln * 4];
            f32x4 o;
            o[0] = bf2f(s4[0]) * rl; o[1] = bf2f(s4[1]) * rl;
            o[2] = bf2f(s4[2]) * rl; o[3] = bf2f(s4[3]) * rl;
            __builtin_nontemporal_store(o, (f32x4*)&out_p[(size_t)q * SN + k0 + ln * 4]);
        }
    }
    __syncthreads();

    float* obuf = (float*)sbuf;
    #pragma unroll
    for (int nt = 0; nt < 4; ++nt) {
        #pragma unroll
        for (int r = 0; r < 4; ++r)
            obuf[(wv * QB + 4 * lg + r) * DN + nt * 16 + lq] = oacc[nt][r];
    }
    __syncthreads();
    #pragma unroll
    for (int i = 0; i < 2; ++i) {
        const int idx = tid + i * 512;
        const int q = idx >> 6, d = idx & 63;
        float v = 0.f;
        #pragma unroll
        for (int w = 0; w < NWAVE; ++w) v += obuf[(w * QB + q) * DN + d];
        out_o[(size_t)q * DN + d] = v * lfin[q];
    }
}

extern "C" void kernel_launch(void* const* d_in, const int* in_sizes, int n_in,
                              void* d_out, int out_size, void* d_ws, size_t ws_size,
                              hipStream_t stream) {
    const float* Q = (const float*)d_in[0];
    const float* K = (const float*)d_in[1];
    const float* V = (const float*)d_in[2];
    const int*   M = (const int*)d_in[3];
    float* out = (float*)d_out;

    const size_t half = (size_t)BN * SN * DN;                 // 2M elems
    const size_t szKp = half * sizeof(short);                 // 4 MB
    const size_t szVt = half * sizeof(short);                 // 4 MB
    const size_t szMf = (size_t)BN * SN * sizeof(float);      // 128 KB
    const size_t szLf = (size_t)BN * SN * sizeof(float);      // 128 KB
    const size_t szPt = (size_t)BN * SN * SN * sizeof(short); // 134 MB
    const size_t need_min  = szKp + szVt + szMf;
    const size_t need_full = need_min + szLf + szPt;

    if (ws_size >= need_full) {
        short* Kp = (short*)d_ws;
        short* Vt = (short*)((char*)d_ws + szKp);
        float* Mf = (float*)((char*)d_ws + szKp + szVt);
        float* Lf = (float*)((char*)d_ws + szKp + szVt + szMf);
        short* Pt = (short*)((char*)d_ws + szKp + szVt + szMf + szLf);
        float* out_p = out + (size_t)BN * SN * DN;
        prep_kv<<<dim3(BN * (SN / 64)), dim3(256), 0, stream>>>(K, V, M, Kp, Vt, Mf);
        attn_pass1<<<dim3(BN * (SN / QB)), dim3(256), 0, stream>>>(Q, Kp, Vt, Mf, Pt, Lf, out);
        scale_p<<<dim3(2048), dim3(256), 0, stream>>>(Pt, Lf, out_p);
    } else if (ws_size >= need_min) {
        short* Kp = (short*)d_ws;
        short* Vt = (short*)((char*)d_ws + szKp);
        float* Mf = (float*)((char*)d_ws + szKp + szVt);
        prep_kv<<<dim3(BN * (SN / 64)), dim3(256), 0, stream>>>(K, V, M, Kp, Vt, Mf);
        attn_fallback<1><<<dim3(BN * (SN / QB)), dim3(512), 0, stream>>>(Q, K, V, M, Kp, Vt, out);
    } else {
        attn_fallback<0><<<dim3(BN * (SN / QB)), dim3(512), 0, stream>>>(Q, K, V, M, nullptr, nullptr, out);
    }
}

// Round 10
// 107.078 us; speedup vs baseline: 2.7523x; 2.7523x over previous
//
#include <hip/hip_runtime.h>
#include <hip/hip_bf16.h>

// Attention fwd with materialized p_attn.
// B=16, S=2048, D=64, f32 in/out. d_out = [out (B,S,D) | p_attn (B,S,S)] f32.
#define BN 16
#define SN 2048
#define DN 64
#define QB 16
#define NWAVE 8           // 512 threads
#define KSEG 256          // keys per wave
#define NCH 8             // chunks (32 keys) per wave

#define SC_L2E 0.18033688011112042f   // 0.125 * log2(e)
#define BI_L2E 11.541560327111707f    // 8 * log2(e): p~ = exp(s - 8)

typedef __attribute__((ext_vector_type(8))) short bf16x8;
typedef __attribute__((ext_vector_type(4))) short bf16x4;
typedef __attribute__((ext_vector_type(4))) float f32x4;
typedef __attribute__((ext_vector_type(4))) int   i32x4;

static __device__ __forceinline__ short f2bf(float f) {
    __hip_bfloat16 h = __float2bfloat16(f);
    union { __hip_bfloat16 h; short s; } u; u.h = h;
    return u.s;
}
static __device__ __forceinline__ float uf(unsigned u) {
    union { unsigned u; float f; } v; v.u = u;
    return v.f;
}
static __device__ __forceinline__ unsigned pk2(float lo, float hi) {
    return ((unsigned)(unsigned short)f2bf(lo)) |
           (((unsigned)(unsigned short)f2bf(hi)) << 16);
}
static __device__ __forceinline__ float fast_exp2(float x) {
#if __has_builtin(__builtin_amdgcn_exp2f)
    return __builtin_amdgcn_exp2f(x);
#else
    return exp2f(x);
#endif
}

// ---- prep: swizzle K and V into MFMA-fragment lane order; mask -> f32 bias ----
// Kf[b][chunk][slot s][lane][8 bf16]: value for lane ln=(lg*16+lq) =
//   K[b][chunk*32 + (s>=2)*16 + lq][(s&1)*32 + 8*lg + j]
// Vf[b][chunk][nt][lane][8 bf16]: j<4 -> V[b][chunk*32+4lg+j][16nt+lq],
//   j>=4 -> V[b][chunk*32+16+4lg+(j-4)][16nt+lq]
// Every hot-loop load becomes base + lane*16B (one cache-line-dense dwordx4).
__global__ __launch_bounds__(256)
void prep_kv(const float* __restrict__ K, const float* __restrict__ V,
             const int* __restrict__ M,
             short* __restrict__ Kf, short* __restrict__ Vf, float* __restrict__ Mf)
{
    __shared__ short vt[64][72];              // V^T staging (72: 16B-aligned rows)
    const int b   = blockIdx.x >> 5;          // 32 groups of 64 keys per batch
    const int s0  = (blockIdx.x & 31) << 6;
    const int cg0 = s0 >> 5;                  // first of 2 chunks in this group
    const int tid = threadIdx.x;
    const int sr = tid >> 4;                  // 0..15
    const int dc = (tid & 15) << 2;           // 0,4,...,60
    #pragma unroll
    for (int i = 0; i < 4; ++i) {
        const int s = sr + i * 16;
        f32x4 vv = *(const f32x4*)(V + ((size_t)b * SN + s0 + s) * DN + dc);
        bf16x4 v4;
        #pragma unroll
        for (int j = 0; j < 4; ++j) v4[j] = f2bf(vv[j]);
        *(bf16x4*)&vt[s][dc] = v4;
    }
    if (tid < 64) {
        const int m = M[(size_t)b * SN + s0 + tid];
        Mf[(size_t)b * SN + s0 + tid] = m ? -BI_L2E : -1e9f;
    }
    __syncthreads();

    // Kf: 512 outputs of 16B (2 chunks x 4 slots x 64 lanes), 2 per thread
    #pragma unroll
    for (int r = 0; r < 2; ++r) {
        const int o   = tid + (r << 8);
        const int h   = o >> 8;
        const int s   = (o >> 6) & 3;
        const int l2  = o & 63;
        const int lq2 = l2 & 15, lg2 = l2 >> 4;
        const int srow = s0 + h * 32 + ((s >> 1) & 1) * 16 + lq2;
        const int scol = (s & 1) * 32 + lg2 * 8;
        const float* kp = K + ((size_t)b * SN + srow) * DN + scol;
        f32x4 x = *(const f32x4*)kp;
        f32x4 y = *(const f32x4*)(kp + 4);
        bf16x8 kv;
        #pragma unroll
        for (int j = 0; j < 4; ++j) { kv[j] = f2bf(x[j]); kv[4 + j] = f2bf(y[j]); }
        *(bf16x8*)(Kf + (size_t)(((b * 64 + cg0 + h) * 4 + s) * 512 + l2 * 8)) = kv;
    }
    // Vf: 512 outputs of 16B (2 chunks x 4 nt x 64 lanes), 2 per thread
    #pragma unroll
    for (int r = 0; r < 2; ++r) {
        const int o   = tid + (r << 8);
        const int h   = o >> 8;
        const int nt  = (o >> 6) & 3;
        const int l2  = o & 63;
        const int lq2 = l2 & 15, lg2 = l2 >> 4;
        const int d   = nt * 16 + lq2;
        bf16x8 w;
        #pragma unroll
        for (int j = 0; j < 4; ++j) {
            w[j]     = vt[h * 32 + 4 * lg2 + j][d];
            w[4 + j] = vt[h * 32 + 16 + 4 * lg2 + j][d];
        }
        *(bf16x8*)(Vf + (size_t)(((b * 64 + cg0 + h) * 4 + nt) * 512 + l2 * 8)) = w;
    }
}

// ---- fused attention: p~ in registers, every hot VMEM op lane-contiguous ----
// Pass A: swapped QK^T (mfma(K,Q)) + exp -> pk[c][0..3] packed bf16 regs + row sum.
// Barrier -> lfin. Pass B: in-place PV (slot-permuted A = pk regs; Vf matches the
// permutation) + p_attn f32 NT stores straight from regs (4 lanes/row = full lines).
template <int PRE>
__global__ __launch_bounds__(512, 2)
void attn_fused(const float* __restrict__ Q, const float* __restrict__ K,
                const float* __restrict__ V, const int* __restrict__ M,
                const short* __restrict__ Kf, const short* __restrict__ Vf,
                const float* __restrict__ Mf, float* __restrict__ out)
{
    __shared__ float obuf[NWAVE * QB * DN];   // 32 KB (epilogue only)
    __shared__ float lred[NWAVE * QB];
    __shared__ float lfin[QB];

    const int tid = threadIdx.x;
    const int wv = tid >> 6, ln = tid & 63;
    const int lq = ln & 15, lg = ln >> 4;

    // XCD-bijective swizzle (2048 blocks / 8 XCDs): 2 batches per XCD.
    const int lb = ((blockIdx.x & 7) << 8) | (blockIdx.x >> 3);
    const int bb = lb >> 7;
    const int q0 = (lb & 127) << 4;

    const float* Qb = Q + ((size_t)bb * SN + q0) * DN;
    float* out_o = out + ((size_t)bb * SN + q0) * DN;
    float* out_p = out + (size_t)BN * SN * DN + ((size_t)bb * SN + q0) * SN;

    // Q fragment (B-operand of swapped QK^T): Q[col=lq][d=8*lg+j]
    bf16x8 qf0, qf1;
    {
        const float* src = Qb + lq * DN + lg * 8;
        f32x4 a = *(const f32x4*)src;
        f32x4 b = *(const f32x4*)(src + 4);
        f32x4 c = *(const f32x4*)(src + 32);
        f32x4 d = *(const f32x4*)(src + 36);
        #pragma unroll
        for (int j = 0; j < 4; ++j) {
            qf0[j] = f2bf(a[j]); qf0[4 + j] = f2bf(b[j]);
            qf1[j] = f2bf(c[j]); qf1[4 + j] = f2bf(d[j]);
        }
    }

    const int k0 = wv * KSEG;
    const int cgb = bb * 64 + wv * NCH;       // this wave's first global chunk
    const short* kfp = Kf + (size_t)cgb * 2048 + ln * 8;
    const short* vfp = Vf + (size_t)cgb * 2048 + ln * 8;
    const float* fp  = Mf + (size_t)bb * SN + k0 + 4 * lg;
    const int*   Mb  = M + (size_t)bb * SN;
    const float* Kb  = K + (size_t)bb * SN * DN;
    const float* Vb  = V + (size_t)bb * SN * DN;

    unsigned pk[NCH][4];
    float lsum = 0.f;

    // ================= pass A: QK^T + exp -> registers =================
    #pragma unroll
    for (int c = 0; c < NCH; ++c) {
        bf16x8 kf0, kf1, kf2, kf3;
        f32x4 b0, b1;
        if constexpr (PRE) {
            kf0 = *(const bf16x8*)(kfp + c * 2048);
            kf1 = *(const bf16x8*)(kfp + c * 2048 + 512);
            kf2 = *(const bf16x8*)(kfp + c * 2048 + 1024);
            kf3 = *(const bf16x8*)(kfp + c * 2048 + 1536);
            b0 = *(const f32x4*)(fp + c * 32);
            b1 = *(const f32x4*)(fp + c * 32 + 16);
        } else {
            const float* ks = Kb + (size_t)(k0 + c * 32 + lq) * DN + lg * 8;
            #pragma unroll
            for (int j = 0; j < 8; ++j) {
                kf0[j] = f2bf(ks[j]);            kf1[j] = f2bf(ks[32 + j]);
                kf2[j] = f2bf(ks[16 * DN + j]);  kf3[j] = f2bf(ks[16 * DN + 32 + j]);
            }
            const i32x4 mv0 = *(const i32x4*)(Mb + k0 + c * 32 + 4 * lg);
            const i32x4 mv1 = *(const i32x4*)(Mb + k0 + c * 32 + 16 + 4 * lg);
            #pragma unroll
            for (int r = 0; r < 4; ++r) {
                b0[r] = mv0[r] ? -BI_L2E : -1e9f;
                b1[r] = mv1[r] ? -BI_L2E : -1e9f;
            }
        }
        f32x4 a0 = {0.f, 0.f, 0.f, 0.f}, a1 = {0.f, 0.f, 0.f, 0.f};
        a0 = __builtin_amdgcn_mfma_f32_16x16x32_bf16(kf0, qf0, a0, 0, 0, 0);
        a0 = __builtin_amdgcn_mfma_f32_16x16x32_bf16(kf1, qf1, a0, 0, 0, 0);
        a1 = __builtin_amdgcn_mfma_f32_16x16x32_bf16(kf2, qf0, a1, 0, 0, 0);
        a1 = __builtin_amdgcn_mfma_f32_16x16x32_bf16(kf3, qf1, a1, 0, 0, 0);

        float p0[4], p1[4];
        #pragma unroll
        for (int r = 0; r < 4; ++r) {
            p0[r] = fast_exp2(fmaf(a0[r], SC_L2E, b0[r]));
            p1[r] = fast_exp2(fmaf(a1[r], SC_L2E, b1[r]));
            lsum += p0[r] + p1[r];
        }
        pk[c][0] = pk2(p0[0], p0[1]); pk[c][1] = pk2(p0[2], p0[3]);
        pk[c][2] = pk2(p1[0], p1[1]); pk[c][3] = pk2(p1[2], p1[3]);
    }

    // row sums (row = lq): reduce over lg groups, then waves via LDS
    lsum += __shfl_xor(lsum, 16);
    lsum += __shfl_xor(lsum, 32);
    if (lg == 0) lred[wv * QB + lq] = lsum;
    __syncthreads();
    if (tid < QB) {
        float l = 0.f;
        #pragma unroll
        for (int w = 0; w < NWAVE; ++w) l += lred[w * QB + tid];
        lfin[tid] = 1.f / l;
    }
    __syncthreads();
    const float rl = lfin[lq];

    // ================= pass B: PV + p stores from registers =================
    f32x4 oacc[4];
    #pragma unroll
    for (int nt = 0; nt < 4; ++nt) oacc[nt] = (f32x4){0.f, 0.f, 0.f, 0.f};
    float* pp = out_p + (size_t)lq * SN + k0 + 4 * lg;

    #pragma unroll
    for (int c = 0; c < NCH; ++c) {
        union { unsigned u[4]; bf16x8 v; } pa;
        pa.u[0] = pk[c][0]; pa.u[1] = pk[c][1];
        pa.u[2] = pk[c][2]; pa.u[3] = pk[c][3];

        bf16x8 vf0, vf1, vf2, vf3;
        if constexpr (PRE) {
            vf0 = *(const bf16x8*)(vfp + c * 2048);
            vf1 = *(const bf16x8*)(vfp + c * 2048 + 512);
            vf2 = *(const bf16x8*)(vfp + c * 2048 + 1024);
            vf3 = *(const bf16x8*)(vfp + c * 2048 + 1536);
        } else {
            #pragma unroll
            for (int j = 0; j < 4; ++j) {
                const float* va = Vb + (size_t)(k0 + c * 32 + 4 * lg + j) * DN + lq;
                const float* vb = Vb + (size_t)(k0 + c * 32 + 16 + 4 * lg + j) * DN + lq;
                vf0[j] = f2bf(va[0]);  vf0[4 + j] = f2bf(vb[0]);
                vf1[j] = f2bf(va[16]); vf1[4 + j] = f2bf(vb[16]);
                vf2[j] = f2bf(va[32]); vf2[4 + j] = f2bf(vb[32]);
                vf3[j] = f2bf(va[48]); vf3[4 + j] = f2bf(vb[48]);
            }
        }
        oacc[0] = __builtin_amdgcn_mfma_f32_16x16x32_bf16(pa.v, vf0, oacc[0], 0, 0, 0);
        oacc[1] = __builtin_amdgcn_mfma_f32_16x16x32_bf16(pa.v, vf1, oacc[1], 0, 0, 0);
        oacc[2] = __builtin_amdgcn_mfma_f32_16x16x32_bf16(pa.v, vf2, oacc[2], 0, 0, 0);
        oacc[3] = __builtin_amdgcn_mfma_f32_16x16x32_bf16(pa.v, vf3, oacc[3], 0, 0, 0);

        // p_attn = p~ * rl straight from regs; 4 lanes (lg 0..3) tile 64B lines
        f32x4 o0, o1;
        o0[0] = uf(pk[c][0] << 16) * rl;  o0[1] = uf(pk[c][0] & 0xffff0000u) * rl;
        o0[2] = uf(pk[c][1] << 16) * rl;  o0[3] = uf(pk[c][1] & 0xffff0000u) * rl;
        o1[0] = uf(pk[c][2] << 16) * rl;  o1[1] = uf(pk[c][2] & 0xffff0000u) * rl;
        o1[2] = uf(pk[c][3] << 16) * rl;  o1[3] = uf(pk[c][3] & 0xffff0000u) * rl;
        __builtin_nontemporal_store(o0, (f32x4*)(pp + c * 32));
        __builtin_nontemporal_store(o1, (f32x4*)(pp + c * 32 + 16));
    }

    // ---- cross-wave O reduce, normalize, write ----
    // oacc[nt][r] = O[q=4lg+r][d=nt*16+lq]
    #pragma unroll
    for (int nt = 0; nt < 4; ++nt) {
        #pragma unroll
        for (int r = 0; r < 4; ++r)
            obuf[(wv * QB + 4 * lg + r) * DN + nt * 16 + lq] = oacc[nt][r];
    }
    __syncthreads();
    #pragma unroll
    for (int i = 0; i < 2; ++i) {
        const int idx = tid + i * 512;
        const int q = idx >> 6, d = idx & 63;
        float v = 0.f;
        #pragma unroll
        for (int w = 0; w < NWAVE; ++w) v += obuf[(w * QB + q) * DN + d];
        out_o[(size_t)q * DN + d] = v * lfin[q];
    }
}

extern "C" void kernel_launch(void* const* d_in, const int* in_sizes, int n_in,
                              void* d_out, int out_size, void* d_ws, size_t ws_size,
                              hipStream_t stream) {
    const float* Q = (const float*)d_in[0];
    const float* K = (const float*)d_in[1];
    const float* V = (const float*)d_in[2];
    const int*   M = (const int*)d_in[3];
    float* out = (float*)d_out;

    const size_t szKf = (size_t)BN * 64 * 4 * 512 * sizeof(short);  // 4 MB
    const size_t szVf = szKf;                                       // 4 MB
    const size_t szMf = (size_t)BN * SN * sizeof(float);            // 128 KB
    const size_t need = szKf + szVf + szMf;

    dim3 block(512);
    dim3 grid(BN * (SN / QB));                                      // 2048 blocks
    if (ws_size >= need) {
        short* Kf = (short*)d_ws;
        short* Vf = (short*)((char*)d_ws + szKf);
        float* Mf = (float*)((char*)d_ws + szKf + szVf);
        prep_kv<<<dim3(BN * (SN / 64)), dim3(256), 0, stream>>>(K, V, M, Kf, Vf, Mf);
        attn_fused<1><<<grid, block, 0, stream>>>(Q, K, V, M, Kf, Vf, Mf, out);
    } else {
        attn_fused<0><<<grid, block, 0, stream>>>(Q, K, V, M, nullptr, nullptr, nullptr, out);
    }
}